// Round 8
// baseline (198.031 us; speedup 1.0000x reference)
//
#include <hip/hip_runtime.h>
#include <math.h>

// ---------------------------------------------------------------------------
// GaitGraph: standardize -> GCN(2->64)+ReLU -> GCN(64->64)+ReLU -> mean-pool
//            -> linear 64->3.   N=50000, E=800000, G=2048, H=64.
// R1: dst-CSR + pull-gather (585 -> 327us).
// R4: rank-2 layer-1 collapse + reg-tile GEMM + sorted pooling (-> 237us).
// R6/R7: layer-2 GEMM/agg swap + gemmB spill fix (-> 187us).
// R8: k_scatter WRITE amp (52.6MB for 6.4MB payload, 42us) attacked:
//     - u16 CSR (src only; weights recomputed via ReLU pos-homogeneity with
//       pre-scaled tables T/Q) -> scatter payload 1.6MB, L2-resident.
//     - k_deg emits packed (dst<<16|src) so scatter reads 3.2MB not 12.8MB.
//     - fuse gath2+gemmB (aggY tile stays in LDS; -25.6MB HBM round trip).
//     Requires N < 65536 (problem has N=50000).
// ---------------------------------------------------------------------------

#define H 64

__device__ __forceinline__ float nan0(float v) {
    return isfinite(v) ? v : 0.0f;
}

// Load index i from a buffer that is either int32 or int64 (flag is64).
__device__ __forceinline__ int ld_idx(const void* p, long long i, int is64) {
    if (is64) return (int)((const long long*)p)[i];
    return ((const int*)p)[i];
}

// Column sums + sumsq of the 2 input features (with nan_to_num).
// Block 0 additionally detects int64 vs int32 for edge_index and batch
// (odd int32 words all zero => int64 high words).
__global__ void k_stats(const float* __restrict__ x, int N,
                        float* __restrict__ stats,
                        const int* ei, int nEi, const int* batch, int nB,
                        int* flags) {
    if (blockIdx.x == 0) {
        __shared__ int nz_e, nz_b;
        if (threadIdx.x == 0) { nz_e = 0; nz_b = 0; }
        __syncthreads();
        int i = threadIdx.x;  // 0..255
        long long pe = 1 + 2 * ((long long)i * ((nEi - 2) / 2) / 256);
        if (pe < nEi && ei[pe] != 0) nz_e = 1;
        long long pb = 1 + 2 * ((long long)i * ((nB - 2) / 2) / 256);
        if (pb < nB && batch[pb] != 0) nz_b = 1;
        __syncthreads();
        if (threadIdx.x == 0) {
            flags[0] = (nz_e == 0);
            flags[1] = (nz_b == 0);
        }
    }
    float s0 = 0, s1 = 0, q0 = 0, q1 = 0;
    int tid = blockIdx.x * blockDim.x + threadIdx.x;
    int stride = gridDim.x * blockDim.x;
    for (int n = tid; n < N; n += stride) {
        float2 v = reinterpret_cast<const float2*>(x)[n];
        float a = nan0(v.x), b = nan0(v.y);
        s0 += a; s1 += b; q0 += a * a; q1 += b * b;
    }
    for (int m = 32; m >= 1; m >>= 1) {
        s0 += __shfl_down(s0, m);
        s1 += __shfl_down(s1, m);
        q0 += __shfl_down(q0, m);
        q1 += __shfl_down(q1, m);
    }
    __shared__ float red[4][4];
    int w = threadIdx.x >> 6, lane = threadIdx.x & 63;
    if (lane == 0) { red[w][0] = s0; red[w][1] = s1; red[w][2] = q0; red[w][3] = q1; }
    __syncthreads();
    if (threadIdx.x == 0) {
        int nw = blockDim.x >> 6;
        float t0 = 0, t1 = 0, t2 = 0, t3 = 0;
        for (int i = 0; i < nw; i++) {
            t0 += red[i][0]; t1 += red[i][1]; t2 += red[i][2]; t3 += red[i][3];
        }
        atomicAdd(&stats[0], t0);
        atomicAdd(&stats[1], t1);
        atomicAdd(&stats[2], t2);
        atomicAdd(&stats[3], t3);
    }
}

// Degree histogram + emit packed edges (dst<<16 | src). One edge read pass.
__global__ void k_degpack(const void* ei, int E, int* __restrict__ counts,
                          unsigned* __restrict__ packed,
                          const int* __restrict__ flags) {
    int e = blockIdx.x * blockDim.x + threadIdx.x;
    if (e >= E) return;
    int is64 = flags[0];
    unsigned s = (unsigned)ld_idx(ei, e, is64);
    unsigned d = (unsigned)ld_idx(ei, (long long)E + e, is64);
    packed[e] = (d << 16) | s;
    atomicAdd(&counts[d], 1);
}

// Block-level exclusive scan of counts + standardized pre-scaled feature
// table T[n] = dinv[n] * (x[n]-mu)/std  (fused; stats already final).
__global__ void k_scan1(const int* __restrict__ counts, int* __restrict__ part,
                        int* __restrict__ bsum, const float* __restrict__ x,
                        const float* __restrict__ stats,
                        float2* __restrict__ T, int N) {
    __shared__ int tmp[256];
    int i = blockIdx.x * 256 + threadIdx.x;
    int v = (i < N) ? counts[i] : 0;
    tmp[threadIdx.x] = v;
    __syncthreads();
    for (int off = 1; off < 256; off <<= 1) {
        int t = (threadIdx.x >= off) ? tmp[threadIdx.x - off] : 0;
        __syncthreads();
        tmp[threadIdx.x] += t;
        __syncthreads();
    }
    if (i < N) {
        part[i] = tmp[threadIdx.x] - v;  // exclusive within block
        float sum0 = stats[0], sum1 = stats[1], q0 = stats[2], q1 = stats[3];
        float mu0 = sum0 / N, mu1 = sum1 / N;
        float v0 = fmaxf((q0 - sum0 * sum0 / N) / (N - 1), 0.0f);
        float v1 = fmaxf((q1 - sum1 * sum1 / N) / (N - 1), 0.0f);
        float r0 = 1.0f / (sqrtf(v0) + 1e-6f);
        float r1 = 1.0f / (sqrtf(v1) + 1e-6f);
        float di = rsqrtf((float)(v + 1));
        float2 xv = reinterpret_cast<const float2*>(x)[i];
        T[i] = make_float2(di * (nan0(xv.x) - mu0) * r0,
                           di * (nan0(xv.y) - mu1) * r1);
    }
    if (threadIdx.x == 255) bsum[blockIdx.x] = tmp[255];
}

__global__ void k_scan2(int* __restrict__ bsum, int nb) {  // nb <= 256
    __shared__ int tmp[256];
    int v = (threadIdx.x < nb) ? bsum[threadIdx.x] : 0;
    tmp[threadIdx.x] = v;
    __syncthreads();
    for (int off = 1; off < 256; off <<= 1) {
        int t = (threadIdx.x >= off) ? tmp[threadIdx.x - off] : 0;
        __syncthreads();
        tmp[threadIdx.x] += t;
        __syncthreads();
    }
    if (threadIdx.x < nb) bsum[threadIdx.x] = tmp[threadIdx.x] - v;
}

__global__ void k_scan3(const int* __restrict__ part, const int* __restrict__ bsum,
                        int* __restrict__ offsets, int* __restrict__ cursor,
                        int N, int E) {
    int i = blockIdx.x * 256 + threadIdx.x;
    if (i < N) {
        int o = part[i] + bsum[blockIdx.x];
        offsets[i] = o;
        cursor[i] = o;
    }
    if (i == 0) offsets[N] = E;
}

// Ticket scatter into u16 CSR (src ids only; 1.6MB, L2-resident).
__global__ void k_scatter16(const unsigned* __restrict__ packed,
                            int* __restrict__ cursor,
                            unsigned short* __restrict__ csr16, int E) {
    int e = blockIdx.x * blockDim.x + threadIdx.x;
    if (e >= E) return;
    unsigned p = packed[e];
    int d = p >> 16;
    int pos = atomicAdd(&cursor[d], 1);
    csr16[pos] = (unsigned short)(p & 0xffffu);
}

// Layer-1 aggregation on pre-scaled T: S[d] = di*(sum_e T[s] + T[d]).
// Emits Q[n] = (S0*di, S1*di, di, 0) for the layer-2 gather.
__global__ void k_aggQ(const unsigned short* __restrict__ csr16,
                       const int* __restrict__ offsets,
                       const float2* __restrict__ T,
                       const int* __restrict__ counts,
                       float4* __restrict__ Q, int N) {
    int n = blockIdx.x * blockDim.x + threadIdx.x;
    if (n >= N) return;
    float di = rsqrtf((float)(counts[n] + 1));
    float2 t = T[n];
    float s0 = t.x, s1 = t.y;  // self term (already dinv-scaled)
    int beg = offsets[n], end = offsets[n + 1];
    for (int k = beg; k < end; k++) {
        float2 ts = T[csr16[k]];
        s0 += ts.x; s1 += ts.y;
    }
    // S = di*(s0,s1); Q = (S*di, di)
    Q[n] = make_float4(s0 * di * di, s1 * di * di, di, 0.0f);
}

// Fused layer-2 aggregation + GEMM + bias + relu.
// Block = 64 dst rows, 256 threads. Phase 1: wave w computes rows
// [w*16, w*16+16): per row, chunked u16-CSR broadcast; per edge contribution
// relu(q0*W1[0][j] + q1*W1[1][j] + q2*b1[j]) (ReLU pos-homogeneity folds the
// edge weight into Q). Row written transposed into LDS. Phase 2: the R7
// register-tile GEMM @W2 + b2 + relu, straight from LDS.
__global__ __launch_bounds__(256, 4) void k_gathgemm(
    const unsigned short* __restrict__ csr16, const int* __restrict__ offsets,
    const float4* __restrict__ Q, const float* __restrict__ W1,
    const float* __restrict__ b1, const float* __restrict__ W2,
    const float* __restrict__ b2, float* __restrict__ Bout, int N) {
    __shared__ float At[64][68];  // At[j][r] = aggY[r][j], pitch 68
    __shared__ float Ws[64][64];
    __shared__ float bs[64];
    int tid = threadIdx.x;
    for (int i = tid; i < 64 * 64; i += 256) Ws[i >> 6][i & 63] = W2[i];
    if (tid < 64) bs[tid] = b2[tid];
    int rbase = blockIdx.x * 64;
    int wid = tid >> 6, j = tid & 63;
    float w10 = W1[j], w11 = W1[H + j], bb = b1[j];
    for (int rr = wid * 16; rr < wid * 16 + 16; rr++) {
        int nn = min(rbase + rr, N - 1);  // clamp; extra rows masked on store
        float4 qd = Q[nn];
        float di = qd.z;
        float acc = fmaxf(qd.x * w10 + qd.y * w11 + qd.z * bb, 0.0f);  // self
        int beg = offsets[nn], end = offsets[nn + 1];
        for (int base = beg; base < end; base += 64) {
            int cnt = min(64, end - base);
            float4 qv;
            if (base + j < end) qv = Q[csr16[base + j]];
            for (int k = 0; k < cnt; k++) {
                float q0 = __shfl(qv.x, k);
                float q1 = __shfl(qv.y, k);
                float q2 = __shfl(qv.z, k);
                acc += fmaxf(q0 * w10 + q1 * w11 + q2 * bb, 0.0f);
            }
        }
        At[j][rr] = di * acc;
    }
    __syncthreads();
    int rg = (tid & 15) * 4;  // row group
    int cg = (tid >> 4) * 4;  // col group
    float acc[4][4] = {{0}};
#pragma unroll 8
    for (int k = 0; k < 64; k++) {
        float4 a = *reinterpret_cast<const float4*>(&At[k][rg]);
        float4 b = *reinterpret_cast<const float4*>(&Ws[k][cg]);
        acc[0][0] += a.x * b.x; acc[0][1] += a.x * b.y;
        acc[0][2] += a.x * b.z; acc[0][3] += a.x * b.w;
        acc[1][0] += a.y * b.x; acc[1][1] += a.y * b.y;
        acc[1][2] += a.y * b.z; acc[1][3] += a.y * b.w;
        acc[2][0] += a.z * b.x; acc[2][1] += a.z * b.y;
        acc[2][2] += a.z * b.z; acc[2][3] += a.z * b.w;
        acc[3][0] += a.w * b.x; acc[3][1] += a.w * b.y;
        acc[3][2] += a.w * b.z; acc[3][3] += a.w * b.w;
    }
#pragma unroll
    for (int i2 = 0; i2 < 4; i2++) {
        int r = rbase + rg + i2;
        if (r < N) {
            *reinterpret_cast<float4*>(&Bout[(size_t)r * H + cg]) = make_float4(
                fmaxf(acc[i2][0] + bs[cg + 0], 0.0f),
                fmaxf(acc[i2][1] + bs[cg + 1], 0.0f),
                fmaxf(acc[i2][2] + bs[cg + 2], 0.0f),
                fmaxf(acc[i2][3] + bs[cg + 3], 0.0f));
        }
    }
}

// Mean-pool per graph (sorted batch; inline binary search) + 64x3 classify.
// Wave per graph; lane j = feature. Searches are wave-uniform.
__global__ __launch_bounds__(256) void k_poolcls(
    const float* __restrict__ B, const void* batch,
    const float* __restrict__ Wc, const float* __restrict__ bc,
    float* __restrict__ out, int N, int G, const int* __restrict__ flags) {
    int t = blockIdx.x * blockDim.x + threadIdx.x;
    int g = t >> 6, j = t & 63;
    if (g >= G) return;
    int is64 = flags[1];
    int beg, end;
    {
        int lo = 0, hi = N;
        while (lo < hi) {
            int mid = (lo + hi) >> 1;
            if (ld_idx(batch, mid, is64) < g) lo = mid + 1; else hi = mid;
        }
        beg = lo;
    }
    {
        int lo = beg, hi = N;
        while (lo < hi) {
            int mid = (lo + hi) >> 1;
            if (ld_idx(batch, mid, is64) < g + 1) lo = mid + 1; else hi = mid;
        }
        end = lo;
    }
    float acc = 0.0f;
    for (int n = beg; n < end; n++) acc += B[(size_t)n * H + j];
    float p = acc / (float)max(end - beg, 1);
#pragma unroll
    for (int c = 0; c < 3; c++) {
        float v = p * Wc[j * 3 + c];
        for (int m = 32; m >= 1; m >>= 1) v += __shfl_xor(v, m);
        if (j == 0) out[g * 3 + c] = v + bc[c];
    }
}

extern "C" void kernel_launch(void* const* d_in, const int* in_sizes, int n_in,
                              void* d_out, int out_size, void* d_ws,
                              size_t ws_size, hipStream_t stream) {
    const float* x  = (const float*)d_in[0];
    const float* W1 = (const float*)d_in[1];
    const float* b1 = (const float*)d_in[2];
    const float* W2 = (const float*)d_in[3];
    const float* b2 = (const float*)d_in[4];
    const float* Wc = (const float*)d_in[5];
    const float* bc = (const float*)d_in[6];
    const void*  ei = d_in[7];
    const void*  batch = d_in[8];

    int N = in_sizes[0] / 2;
    int E = in_sizes[7] / 2;
    int G = out_size / 3;

    // Workspace layout (descending alignment).
    float4* Q       = (float4*)d_ws;                       // [N]   800KB
    float*  B       = (float*)(Q + N);                     // [N,64] 12.8MB
    float2* T       = (float2*)(B + (size_t)N * H);        // [N]   400KB
    unsigned* packed = (unsigned*)(T + N);                 // [E]   3.2MB
    unsigned short* csr16 = (unsigned short*)(packed + E); // [E]   1.6MB
    int*    counts  = (int*)(csr16 + E);                   // [N] (E even -> 4B ok)
    int*    part    = counts + N;                          // [N]
    int*    bsum    = part + N;                            // [256]
    int*    offsets = bsum + 256;                          // [N+1]
    int*    cursor  = offsets + N + 1;                     // [N]
    float*  stats   = (float*)(cursor + N);                // [8]
    int*    flags   = (int*)(stats + 8);                   // [2]

    float* out = (float*)d_out;

    int nblk_n256 = (N + 255) / 256;
    int nblk_e = (E + 255) / 256;

    hipMemsetAsync(stats, 0, 8 * sizeof(float), stream);
    hipMemsetAsync(counts, 0, (size_t)N * sizeof(int), stream);

    k_stats<<<128, 256, 0, stream>>>(x, N, stats, (const int*)ei, in_sizes[7],
                                     (const int*)batch, in_sizes[8], flags);

    // CSR build (u16 entries)
    k_degpack<<<nblk_e, 256, 0, stream>>>(ei, E, counts, packed, flags);
    k_scan1<<<nblk_n256, 256, 0, stream>>>(counts, part, bsum, x, stats, T, N);
    k_scan2<<<1, 256, 0, stream>>>(bsum, nblk_n256);
    k_scan3<<<nblk_n256, 256, 0, stream>>>(part, bsum, offsets, cursor, N, E);
    k_scatter16<<<nblk_e, 256, 0, stream>>>(packed, cursor, csr16, E);

    // Layer 1 (pre-scaled rank-2 aggregation) -> Q table
    k_aggQ<<<nblk_n256, 256, 0, stream>>>(csr16, offsets, T, counts, Q, N);

    // Layer 2: fused aggregation + GEMM + bias + relu
    k_gathgemm<<<(N + 63) / 64, 256, 0, stream>>>(csr16, offsets, Q, W1, b1,
                                                  W2, b2, B, N);

    // Pool + classify (sorted batch, inline search)
    k_poolcls<<<(G * H + 255) / 256, 256, 0, stream>>>(B, batch, Wc, bc, out,
                                                       N, G, flags);
}

// Round 9
// 181.163 us; speedup vs baseline: 1.0931x; 1.0931x over previous
//
#include <hip/hip_runtime.h>
#include <math.h>

// ---------------------------------------------------------------------------
// GaitGraph: standardize -> GCN(2->64)+ReLU -> GCN(64->64)+ReLU -> mean-pool
//            -> linear 64->3.   N=50000, E=800000, G=2048, H=64.
// R1: dst-CSR + pull-gather (585 -> 327us).
// R4: rank-2 layer-1 collapse + reg-tile GEMM + sorted pooling (-> 237us).
// R6/R7: layer-2 GEMM/agg swap + gemmB spill fix (-> 187us).
// R8: u16 CSR + packed degpack (scatter WRITE amp fixed) + gath/gemm fusion.
//     Fusion regressed: 3 bpermutes/edge x 16-rows-per-wave serial = DS-pipe
//     latency bound at 27% VALUBusy (57us).
// R9: phase-1 rewrite: wave's 16 rows = contiguous CSR range; flat 64-edge
//     chunks -> full-width gathers; per-edge broadcast ds_read_b128 from a
//     per-wave LDS chunk (1 DS op/edge instead of 3 bpermutes).
// ---------------------------------------------------------------------------

#define H 64

__device__ __forceinline__ float nan0(float v) {
    return isfinite(v) ? v : 0.0f;
}

// Load index i from a buffer that is either int32 or int64 (flag is64).
__device__ __forceinline__ int ld_idx(const void* p, long long i, int is64) {
    if (is64) return (int)((const long long*)p)[i];
    return ((const int*)p)[i];
}

// Column sums + sumsq of the 2 input features (with nan_to_num).
// Block 0 additionally detects int64 vs int32 for edge_index and batch
// (odd int32 words all zero => int64 high words).
__global__ void k_stats(const float* __restrict__ x, int N,
                        float* __restrict__ stats,
                        const int* ei, int nEi, const int* batch, int nB,
                        int* flags) {
    if (blockIdx.x == 0) {
        __shared__ int nz_e, nz_b;
        if (threadIdx.x == 0) { nz_e = 0; nz_b = 0; }
        __syncthreads();
        int i = threadIdx.x;  // 0..255
        long long pe = 1 + 2 * ((long long)i * ((nEi - 2) / 2) / 256);
        if (pe < nEi && ei[pe] != 0) nz_e = 1;
        long long pb = 1 + 2 * ((long long)i * ((nB - 2) / 2) / 256);
        if (pb < nB && batch[pb] != 0) nz_b = 1;
        __syncthreads();
        if (threadIdx.x == 0) {
            flags[0] = (nz_e == 0);
            flags[1] = (nz_b == 0);
        }
    }
    float s0 = 0, s1 = 0, q0 = 0, q1 = 0;
    int tid = blockIdx.x * blockDim.x + threadIdx.x;
    int stride = gridDim.x * blockDim.x;
    for (int n = tid; n < N; n += stride) {
        float2 v = reinterpret_cast<const float2*>(x)[n];
        float a = nan0(v.x), b = nan0(v.y);
        s0 += a; s1 += b; q0 += a * a; q1 += b * b;
    }
    for (int m = 32; m >= 1; m >>= 1) {
        s0 += __shfl_down(s0, m);
        s1 += __shfl_down(s1, m);
        q0 += __shfl_down(q0, m);
        q1 += __shfl_down(q1, m);
    }
    __shared__ float red[4][4];
    int w = threadIdx.x >> 6, lane = threadIdx.x & 63;
    if (lane == 0) { red[w][0] = s0; red[w][1] = s1; red[w][2] = q0; red[w][3] = q1; }
    __syncthreads();
    if (threadIdx.x == 0) {
        int nw = blockDim.x >> 6;
        float t0 = 0, t1 = 0, t2 = 0, t3 = 0;
        for (int i = 0; i < nw; i++) {
            t0 += red[i][0]; t1 += red[i][1]; t2 += red[i][2]; t3 += red[i][3];
        }
        atomicAdd(&stats[0], t0);
        atomicAdd(&stats[1], t1);
        atomicAdd(&stats[2], t2);
        atomicAdd(&stats[3], t3);
    }
}

// Degree histogram + emit packed edges (dst<<16 | src). One edge read pass.
__global__ void k_degpack(const void* ei, int E, int* __restrict__ counts,
                          unsigned* __restrict__ packed,
                          const int* __restrict__ flags) {
    int e = blockIdx.x * blockDim.x + threadIdx.x;
    if (e >= E) return;
    int is64 = flags[0];
    unsigned s = (unsigned)ld_idx(ei, e, is64);
    unsigned d = (unsigned)ld_idx(ei, (long long)E + e, is64);
    packed[e] = (d << 16) | s;
    atomicAdd(&counts[d], 1);
}

// Block-level exclusive scan of counts + standardized pre-scaled feature
// table T[n] = dinv[n] * (x[n]-mu)/std  (fused; stats already final).
__global__ void k_scan1(const int* __restrict__ counts, int* __restrict__ part,
                        int* __restrict__ bsum, const float* __restrict__ x,
                        const float* __restrict__ stats,
                        float2* __restrict__ T, int N) {
    __shared__ int tmp[256];
    int i = blockIdx.x * 256 + threadIdx.x;
    int v = (i < N) ? counts[i] : 0;
    tmp[threadIdx.x] = v;
    __syncthreads();
    for (int off = 1; off < 256; off <<= 1) {
        int t = (threadIdx.x >= off) ? tmp[threadIdx.x - off] : 0;
        __syncthreads();
        tmp[threadIdx.x] += t;
        __syncthreads();
    }
    if (i < N) {
        part[i] = tmp[threadIdx.x] - v;  // exclusive within block
        float sum0 = stats[0], sum1 = stats[1], q0 = stats[2], q1 = stats[3];
        float mu0 = sum0 / N, mu1 = sum1 / N;
        float v0 = fmaxf((q0 - sum0 * sum0 / N) / (N - 1), 0.0f);
        float v1 = fmaxf((q1 - sum1 * sum1 / N) / (N - 1), 0.0f);
        float r0 = 1.0f / (sqrtf(v0) + 1e-6f);
        float r1 = 1.0f / (sqrtf(v1) + 1e-6f);
        float di = rsqrtf((float)(v + 1));
        float2 xv = reinterpret_cast<const float2*>(x)[i];
        T[i] = make_float2(di * (nan0(xv.x) - mu0) * r0,
                           di * (nan0(xv.y) - mu1) * r1);
    }
    if (threadIdx.x == 255) bsum[blockIdx.x] = tmp[255];
}

__global__ void k_scan2(int* __restrict__ bsum, int nb) {  // nb <= 256
    __shared__ int tmp[256];
    int v = (threadIdx.x < nb) ? bsum[threadIdx.x] : 0;
    tmp[threadIdx.x] = v;
    __syncthreads();
    for (int off = 1; off < 256; off <<= 1) {
        int t = (threadIdx.x >= off) ? tmp[threadIdx.x - off] : 0;
        __syncthreads();
        tmp[threadIdx.x] += t;
        __syncthreads();
    }
    if (threadIdx.x < nb) bsum[threadIdx.x] = tmp[threadIdx.x] - v;
}

__global__ void k_scan3(const int* __restrict__ part, const int* __restrict__ bsum,
                        int* __restrict__ offsets, int* __restrict__ cursor,
                        int N, int E) {
    int i = blockIdx.x * 256 + threadIdx.x;
    if (i < N) {
        int o = part[i] + bsum[blockIdx.x];
        offsets[i] = o;
        cursor[i] = o;
    }
    if (i == 0) offsets[N] = E;
}

// Ticket scatter into u16 CSR (src ids only; 1.6MB, L2-resident).
__global__ void k_scatter16(const unsigned* __restrict__ packed,
                            int* __restrict__ cursor,
                            unsigned short* __restrict__ csr16, int E) {
    int e = blockIdx.x * blockDim.x + threadIdx.x;
    if (e >= E) return;
    unsigned p = packed[e];
    int d = p >> 16;
    int pos = atomicAdd(&cursor[d], 1);
    csr16[pos] = (unsigned short)(p & 0xffffu);
}

// Layer-1 aggregation on pre-scaled T: S[d] = di*(sum_e T[s] + T[d]).
// Emits Q[n] = (S0*di, S1*di, di, 0) for the layer-2 gather.
__global__ void k_aggQ(const unsigned short* __restrict__ csr16,
                       const int* __restrict__ offsets,
                       const float2* __restrict__ T,
                       const int* __restrict__ counts,
                       float4* __restrict__ Q, int N) {
    int n = blockIdx.x * blockDim.x + threadIdx.x;
    if (n >= N) return;
    float di = rsqrtf((float)(counts[n] + 1));
    float2 t = T[n];
    float s0 = t.x, s1 = t.y;  // self term (already dinv-scaled)
    int beg = offsets[n], end = offsets[n + 1];
    for (int k = beg; k < end; k++) {
        float2 ts = T[csr16[k]];
        s0 += ts.x; s1 += ts.y;
    }
    // S = di*(s0,s1); Q = (S*di, di)
    Q[n] = make_float4(s0 * di * di, s1 * di * di, di, 0.0f);
}

// Fused layer-2 aggregation + GEMM + bias + relu.
// Block = 64 dst rows, 256 threads; wave w owns rows [w*16, w*16+16), whose
// edges are one CONTIGUOUS u16-CSR range (CSR is dst-sorted). Phase 1:
// flat-iterate that range in 64-edge chunks: full-width gather of Q entries
// into a per-wave LDS chunk, then per edge one broadcast ds_read_b128 + 5
// VALU (relu pos-homogeneity folds the edge weight into Q). Row boundaries
// advance with wave-uniform logic. Phase 2: register-tile GEMM @W2+b2+relu.
__global__ __launch_bounds__(256, 4) void k_gathgemm(
    const unsigned short* __restrict__ csr16, const int* __restrict__ offsets,
    const float4* __restrict__ Q, const float* __restrict__ W1,
    const float* __restrict__ b1, const float* __restrict__ W2,
    const float* __restrict__ b2, float* __restrict__ Bout, int N) {
    __shared__ float At[64][68];      // At[j][r] = aggY[r][j], pitch 68
    __shared__ float Ws[64][64];
    __shared__ float bs[64];
    __shared__ float4 chunkW[4][64];  // per-wave gathered Q entries
    int tid = threadIdx.x;
    for (int i = tid; i < 64 * 64; i += 256) Ws[i >> 6][i & 63] = W2[i];
    if (tid < 64) bs[tid] = b2[tid];
    int rbase = blockIdx.x * 64;
    int wid = tid >> 6, j = tid & 63;
    float w10 = W1[j], w11 = W1[H + j], bb = b1[j];

    int r0 = min(rbase + wid * 16, N);
    int r1 = min(r0 + 16, N);
    if (r0 < r1) {
        int eEnd = offsets[r1];
        int row = r0;
        int rowEnd = offsets[row + 1];
        float4 qd = Q[row];
        float di = qd.z;
        float acc = fmaxf(qd.x * w10 + qd.y * w11 + qd.z * bb, 0.0f);  // self
        for (int base = offsets[r0]; base < eEnd; base += 64) {
            if (base + j < eEnd) chunkW[wid][j] = Q[csr16[base + j]];
            int cnt = min(64, eEnd - base);
            for (int k = 0; k < cnt; k++) {
                int ecur = base + k;            // wave-uniform
                while (ecur >= rowEnd) {        // row(s) complete
                    At[j][row - rbase] = di * acc;
                    row++;
                    rowEnd = offsets[row + 1];
                    qd = Q[row];
                    di = qd.z;
                    acc = fmaxf(qd.x * w10 + qd.y * w11 + qd.z * bb, 0.0f);
                }
                float4 q = chunkW[wid][k];      // LDS broadcast read
                acc += fmaxf(q.x * w10 + q.y * w11 + q.z * bb, 0.0f);
            }
        }
        // Flush remaining rows (incl. zero-degree tail).
        while (row < r1) {
            At[j][row - rbase] = di * acc;
            row++;
            if (row < r1) {
                rowEnd = offsets[row + 1];
                qd = Q[row];
                di = qd.z;
                acc = fmaxf(qd.x * w10 + qd.y * w11 + qd.z * bb, 0.0f);
            }
        }
    }
    __syncthreads();
    int rg = (tid & 15) * 4;  // row group
    int cg = (tid >> 4) * 4;  // col group
    float acc2[4][4] = {{0}};
#pragma unroll 8
    for (int k = 0; k < 64; k++) {
        float4 a = *reinterpret_cast<const float4*>(&At[k][rg]);
        float4 b = *reinterpret_cast<const float4*>(&Ws[k][cg]);
        acc2[0][0] += a.x * b.x; acc2[0][1] += a.x * b.y;
        acc2[0][2] += a.x * b.z; acc2[0][3] += a.x * b.w;
        acc2[1][0] += a.y * b.x; acc2[1][1] += a.y * b.y;
        acc2[1][2] += a.y * b.z; acc2[1][3] += a.y * b.w;
        acc2[2][0] += a.z * b.x; acc2[2][1] += a.z * b.y;
        acc2[2][2] += a.z * b.z; acc2[2][3] += a.z * b.w;
        acc2[3][0] += a.w * b.x; acc2[3][1] += a.w * b.y;
        acc2[3][2] += a.w * b.z; acc2[3][3] += a.w * b.w;
    }
#pragma unroll
    for (int i2 = 0; i2 < 4; i2++) {
        int r = rbase + rg + i2;
        if (r < N) {
            *reinterpret_cast<float4*>(&Bout[(size_t)r * H + cg]) = make_float4(
                fmaxf(acc2[i2][0] + bs[cg + 0], 0.0f),
                fmaxf(acc2[i2][1] + bs[cg + 1], 0.0f),
                fmaxf(acc2[i2][2] + bs[cg + 2], 0.0f),
                fmaxf(acc2[i2][3] + bs[cg + 3], 0.0f));
        }
    }
}

// Mean-pool per graph (sorted batch; inline binary search) + 64x3 classify.
// Wave per graph; lane j = feature. Searches are wave-uniform.
__global__ __launch_bounds__(256) void k_poolcls(
    const float* __restrict__ B, const void* batch,
    const float* __restrict__ Wc, const float* __restrict__ bc,
    float* __restrict__ out, int N, int G, const int* __restrict__ flags) {
    int t = blockIdx.x * blockDim.x + threadIdx.x;
    int g = t >> 6, j = t & 63;
    if (g >= G) return;
    int is64 = flags[1];
    int beg, end;
    {
        int lo = 0, hi = N;
        while (lo < hi) {
            int mid = (lo + hi) >> 1;
            if (ld_idx(batch, mid, is64) < g) lo = mid + 1; else hi = mid;
        }
        beg = lo;
    }
    {
        int lo = beg, hi = N;
        while (lo < hi) {
            int mid = (lo + hi) >> 1;
            if (ld_idx(batch, mid, is64) < g + 1) lo = mid + 1; else hi = mid;
        }
        end = lo;
    }
    float acc = 0.0f;
    for (int n = beg; n < end; n++) acc += B[(size_t)n * H + j];
    float p = acc / (float)max(end - beg, 1);
#pragma unroll
    for (int c = 0; c < 3; c++) {
        float v = p * Wc[j * 3 + c];
        for (int m = 32; m >= 1; m >>= 1) v += __shfl_xor(v, m);
        if (j == 0) out[g * 3 + c] = v + bc[c];
    }
}

extern "C" void kernel_launch(void* const* d_in, const int* in_sizes, int n_in,
                              void* d_out, int out_size, void* d_ws,
                              size_t ws_size, hipStream_t stream) {
    const float* x  = (const float*)d_in[0];
    const float* W1 = (const float*)d_in[1];
    const float* b1 = (const float*)d_in[2];
    const float* W2 = (const float*)d_in[3];
    const float* b2 = (const float*)d_in[4];
    const float* Wc = (const float*)d_in[5];
    const float* bc = (const float*)d_in[6];
    const void*  ei = d_in[7];
    const void*  batch = d_in[8];

    int N = in_sizes[0] / 2;
    int E = in_sizes[7] / 2;
    int G = out_size / 3;

    // Workspace layout (descending alignment).
    float4* Q       = (float4*)d_ws;                       // [N]   800KB
    float*  B       = (float*)(Q + N);                     // [N,64] 12.8MB
    float2* T       = (float2*)(B + (size_t)N * H);        // [N]   400KB
    unsigned* packed = (unsigned*)(T + N);                 // [E]   3.2MB
    unsigned short* csr16 = (unsigned short*)(packed + E); // [E]   1.6MB
    int*    counts  = (int*)(csr16 + E);                   // [N] (E even -> 4B ok)
    int*    part    = counts + N;                          // [N]
    int*    bsum    = part + N;                            // [256]
    int*    offsets = bsum + 256;                          // [N+1]
    int*    cursor  = offsets + N + 1;                     // [N]
    float*  stats   = (float*)(cursor + N);                // [8]
    int*    flags   = (int*)(stats + 8);                   // [2]

    float* out = (float*)d_out;

    int nblk_n256 = (N + 255) / 256;
    int nblk_e = (E + 255) / 256;

    hipMemsetAsync(stats, 0, 8 * sizeof(float), stream);
    hipMemsetAsync(counts, 0, (size_t)N * sizeof(int), stream);

    k_stats<<<128, 256, 0, stream>>>(x, N, stats, (const int*)ei, in_sizes[7],
                                     (const int*)batch, in_sizes[8], flags);

    // CSR build (u16 entries)
    k_degpack<<<nblk_e, 256, 0, stream>>>(ei, E, counts, packed, flags);
    k_scan1<<<nblk_n256, 256, 0, stream>>>(counts, part, bsum, x, stats, T, N);
    k_scan2<<<1, 256, 0, stream>>>(bsum, nblk_n256);
    k_scan3<<<nblk_n256, 256, 0, stream>>>(part, bsum, offsets, cursor, N, E);
    k_scatter16<<<nblk_e, 256, 0, stream>>>(packed, cursor, csr16, E);

    // Layer 1 (pre-scaled rank-2 aggregation) -> Q table
    k_aggQ<<<nblk_n256, 256, 0, stream>>>(csr16, offsets, T, counts, Q, N);

    // Layer 2: fused aggregation + GEMM + bias + relu
    k_gathgemm<<<(N + 63) / 64, 256, 0, stream>>>(csr16, offsets, Q, W1, b1,
                                                  W2, b2, B, N);

    // Pool + classify (sorted batch, inline search)
    k_poolcls<<<(G * H + 255) / 256, 256, 0, stream>>>(B, batch, Wc, bc, out,
                                                       N, G, flags);
}